// Round 4
// baseline (5530.014 us; speedup 1.0000x reference)
//
#include <hip/hip_runtime.h>
#include <math.h>

// ---------------------------------------------------------------------------
// R4: convs/BN-stats/params/residual stay exact f64 (cheap, anchors margins).
// ODE dopri loop switches to f32: f32 LDS weights, 1-instr readlane bcast,
// v_fmac_f32, erff/expf. R3 was VALU issue-bound (98% busy) with 8 issued
// instrs per 2 half-rate f64 FMAs; f32 cuts per-feval issue ~3x.
// Risk gate: if spike bits flip (absmax 1.0) -> revert ODE to f64 next round.
// ---------------------------------------------------------------------------

#define NELEM (16 * 64 * 64 * 64)  // 4194304, B*C*H*W with C=64

__device__ double g_y1[NELEM];    // conv1 out (f64) -> overwritten in-place by spike1
__device__ double g_ysc[NELEM];   // 1x1 shortcut conv out (f64)
__device__ double g_y2[NELEM];    // conv2 out (f64)
__device__ double g_part[384][1024];  // per-block stat partials
__device__ double g_stats[384];
__device__ double g_prm[384];     // [0]=bn1 sc,[64]=bn1 sh,[128]=sc sc,[192]=sc sh,
                                  // [256]=bn2 sc,[320]=bn2 sh
__device__ double g_w1d[64 * 32 * 9];
__device__ double g_b1d[64];
__device__ double g_scwd[64 * 32];
__device__ double g_w2d[64 * 64 * 9];

// ---------------- weight upconvert (f32 -> f64, exact) ----------------------
__global__ void prep_kernel(const float* __restrict__ w1, const float* __restrict__ b1,
                            const float* __restrict__ scw, const float* __restrict__ w2)
{
  int i = blockIdx.x * 256 + threadIdx.x;
  if (i < 64 * 32 * 9) g_w1d[i] = (double)w1[i];
  if (i < 64)          g_b1d[i] = (double)b1[i];
  if (i < 64 * 32)     g_scwd[i] = (double)scw[i];
  if (i < 64 * 64 * 9) g_w2d[i] = (double)w2[i];
}

__device__ __forceinline__ double wave_sum64(double v) {
#pragma unroll
  for (int m = 1; m < 64; m <<= 1) v += __shfl_xor(v, m);
  return v;
}

// ---------------- conv1 (3x3, 32->64, bias) + sc conv (1x1) -----------------
__global__ __launch_bounds__(256) void conv1_sc_kernel(const float* __restrict__ x)
{
  const int b = blockIdx.x >> 6, h = blockIdx.x & 63;
  const int w = threadIdx.x & 63;
  const int cog = __builtin_amdgcn_readfirstlane(threadIdx.x >> 6);  // 0..3
  __shared__ float xs[3][32][64];
  for (int i = threadIdx.x; i < 3 * 32 * 64; i += 256) {
    int kh = i >> 11, ci = (i >> 6) & 31, ww = i & 63;
    int hh = h + kh - 1;
    xs[kh][ci][ww] = ((unsigned)hh < 64u) ? x[((b * 32 + ci) << 12) + (hh << 6) + ww] : 0.f;
  }
  __syncthreads();

  double acc[16], asc[16];
#pragma unroll
  for (int i = 0; i < 16; ++i) { acc[i] = g_b1d[cog * 16 + i]; asc[i] = 0.0; }

  for (int ci = 0; ci < 32; ++ci) {
    double xv[3][3];
#pragma unroll
    for (int kh = 0; kh < 3; ++kh) {
      xv[kh][0] = (w > 0)  ? (double)xs[kh][ci][w - 1] : 0.0;
      xv[kh][1] = (double)xs[kh][ci][w];
      xv[kh][2] = (w < 63) ? (double)xs[kh][ci][w + 1] : 0.0;
    }
#pragma unroll
    for (int i = 0; i < 16; ++i) {
      const int co = cog * 16 + i;
      const double* wp = &g_w1d[(co * 32 + ci) * 9];
      double a = acc[i];
#pragma unroll
      for (int k = 0; k < 9; ++k) a = fma(xv[k / 3][k % 3], wp[k], a);
      acc[i] = a;
      asc[i] = fma(xv[1][1], g_scwd[co * 32 + ci], asc[i]);
    }
  }

#pragma unroll
  for (int i = 0; i < 16; ++i) {
    const int co = cog * 16 + i;
    const int oidx = ((b * 64 + co) << 12) + (h << 6) + w;
    double v = acc[i], u = asc[i];
    g_y1[oidx] = v;
    g_ysc[oidx] = u;
    double s = wave_sum64(v), q = wave_sum64(v * v);
    double ss = wave_sum64(u), qq = wave_sum64(u * u);
    if (w == 0) {
      g_part[co][blockIdx.x] = s;        g_part[64 + co][blockIdx.x] = q;
      g_part[128 + co][blockIdx.x] = ss; g_part[192 + co][blockIdx.x] = qq;
    }
  }
}

// ---------------- conv2 (3x3, 64->64, no bias) ------------------------------
__global__ __launch_bounds__(256) void conv2_kernel()
{
  const int b = blockIdx.x >> 6, h = blockIdx.x & 63;
  const int w = threadIdx.x & 63;
  const int cog = __builtin_amdgcn_readfirstlane(threadIdx.x >> 6);
  __shared__ float xs[3][64][64];   // spike values {0,1}: f32 exact
  for (int i = threadIdx.x; i < 3 * 64 * 64; i += 256) {
    int kh = i >> 12, ci = (i >> 6) & 63, ww = i & 63;
    int hh = h + kh - 1;
    xs[kh][ci][ww] = ((unsigned)hh < 64u) ? (float)g_y1[((b * 64 + ci) << 12) + (hh << 6) + ww] : 0.f;
  }
  __syncthreads();

  double acc[16];
#pragma unroll
  for (int i = 0; i < 16; ++i) acc[i] = 0.0;

  for (int ci = 0; ci < 64; ++ci) {
    double xv[3][3];
#pragma unroll
    for (int kh = 0; kh < 3; ++kh) {
      xv[kh][0] = (w > 0)  ? (double)xs[kh][ci][w - 1] : 0.0;
      xv[kh][1] = (double)xs[kh][ci][w];
      xv[kh][2] = (w < 63) ? (double)xs[kh][ci][w + 1] : 0.0;
    }
#pragma unroll
    for (int i = 0; i < 16; ++i) {
      const int co = cog * 16 + i;
      const double* wp = &g_w2d[(co * 64 + ci) * 9];
      double a = acc[i];
#pragma unroll
      for (int k = 0; k < 9; ++k) a = fma(xv[k / 3][k % 3], wp[k], a);
      acc[i] = a;
    }
  }

#pragma unroll
  for (int i = 0; i < 16; ++i) {
    const int co = cog * 16 + i;
    double v = acc[i];
    g_y2[((b * 64 + co) << 12) + (h << 6) + w] = v;
    double s = wave_sum64(v), q = wave_sum64(v * v);
    if (w == 0) { g_part[256 + co][blockIdx.x] = s; g_part[320 + co][blockIdx.x] = q; }
  }
}

// ---------------- deterministic stat reduction ------------------------------
__global__ __launch_bounds__(256) void reduce_stats(int base)
{
  const int row = base + blockIdx.x;
  const int t = threadIdx.x;
  double s = g_part[row][t] + g_part[row][t + 256] + g_part[row][t + 512] + g_part[row][t + 768];
  s = wave_sum64(s);
  __shared__ double ls[4];
  if ((t & 63) == 0) ls[t >> 6] = s;
  __syncthreads();
  if (t == 0) g_stats[row] = ls[0] + ls[1] + ls[2] + ls[3];
}

// ---------------- BN params: scale = g*rstd, shift = b - m*scale ------------
__global__ void bn_params(int s_off, int q_off, int p_off,
                          const float* __restrict__ g, const float* __restrict__ bta)
{
  int c = threadIdx.x;
  const double inv = 1.0 / 65536.0;
  double m = g_stats[s_off + c] * inv;
  double v = g_stats[q_off + c] * inv - m * m;
  double rstd = 1.0 / sqrt(v + 1e-5);
  double sc = (double)g[c] * rstd;
  g_prm[p_off + c] = sc;
  g_prm[p_off + 64 + c] = (double)bta[c] - m * sc;
}

// ---------------- ODE (dopri5, 5 steps, f32) + spike [+ residual] -----------
// f32 weights in LDS; wos row-major (lane j = column j), wts transposed.
// One row per wave; x broadcast via 1-instr readlane.
__device__ __forceinline__ float bcast_f(float v, int l) {
  return __uint_as_float(__builtin_amdgcn_readlane(__float_as_uint(v), l));
}

template <bool RES>
__global__ __launch_bounds__(256, 4) void ode_kernel(
    int prm_off, const float* __restrict__ wodep, const float* __restrict__ wtgp,
    const float* __restrict__ tgbp, float thr, float* __restrict__ outf)
{
  __shared__ float wos[64 * 64];
  __shared__ float wts[64 * 64];
  for (int t = threadIdx.x; t < 4096; t += 256) {
    wos[t] = wodep[t];
    int i = t >> 6, j = t & 63;
    wts[t] = wtgp[j * 64 + i];
  }
  __syncthreads();

  const int lane = threadIdx.x & 63;
  const int wv = __builtin_amdgcn_readfirstlane(threadIdx.x >> 6);
  const float tb = tgbp[lane];

  auto feval = [&](float xsv) -> float {
    float ao0 = 0.f, ao1 = 0.f, ao2 = 0.f, ao3 = 0.f;
    float at0 = 0.f, at1 = 0.f, at2 = 0.f, at3 = 0.f;
#pragma unroll
    for (int i = 0; i < 64; i += 4) {
      float x0 = bcast_f(xsv, i);
      float x1 = bcast_f(xsv, i + 1);
      float x2 = bcast_f(xsv, i + 2);
      float x3 = bcast_f(xsv, i + 3);
      ao0 = fmaf(x0, wos[(i + 0) * 64 + lane], ao0);
      at0 = fmaf(x0, wts[(i + 0) * 64 + lane], at0);
      ao1 = fmaf(x1, wos[(i + 1) * 64 + lane], ao1);
      at1 = fmaf(x1, wts[(i + 1) * 64 + lane], at1);
      ao2 = fmaf(x2, wos[(i + 2) * 64 + lane], ao2);
      at2 = fmaf(x2, wts[(i + 2) * 64 + lane], at2);
      ao3 = fmaf(x3, wos[(i + 3) * 64 + lane], ao3);
      at3 = fmaf(x3, wts[(i + 3) * 64 + lane], at3);
    }
    float ao = (ao0 + ao1) + (ao2 + ao3);
    float z = ((at0 + at1) + (at2 + at3)) + tb;
    float g = 0.5f * ao * (1.f + erff(ao * 0.70710678118654752440f));
    float s = 1.f / (1.f + expf(-z));       // sigmoid (expf inf -> s=0, ok)
    float tf = 1.f / (1.f + s);
    return g * tf;
  };

  const float H = (float)(1.0 / 5.0);
  const float A21 = (float)(1.0 / 5.0);
  const float A31 = (float)(3.0 / 40.0), A32 = (float)(9.0 / 40.0);
  const float A41 = (float)(44.0 / 45.0), A42 = (float)(-56.0 / 15.0), A43 = (float)(32.0 / 9.0);
  const float A51 = (float)(19372.0 / 6561.0), A52 = (float)(-25360.0 / 2187.0),
              A53 = (float)(64448.0 / 6561.0), A54 = (float)(-212.0 / 729.0);
  const float A61 = (float)(9017.0 / 3168.0), A62 = (float)(-355.0 / 33.0),
              A63 = (float)(46732.0 / 5247.0), A64 = (float)(49.0 / 176.0),
              A65 = (float)(-5103.0 / 18656.0);
  const float B1 = (float)(35.0 / 384.0), B3 = (float)(500.0 / 1113.0),
              B4 = (float)(125.0 / 192.0), B5 = (float)(-2187.0 / 6784.0),
              B6 = (float)(11.0 / 84.0);

  const int row = blockIdx.x * 4 + wv;      // one row per wave
  const int c = (row >> 6) & 63;
  const int idx = (row << 6) + lane;
  const double psc = g_prm[prm_off + c], psh = g_prm[prm_off + 64 + c];
  float xv = (float)fma(RES ? g_y2[idx] : g_y1[idx], psc, psh);  // exact BN in f64

#pragma unroll 1
  for (int st5 = 0; st5 < 5; ++st5) {
    float k1 = feval(xv);
    float k2 = feval(xv + H * (A21 * k1));
    float k3 = feval(xv + H * (A31 * k1 + A32 * k2));
    float k4 = feval(xv + H * (A41 * k1 + A42 * k2 + A43 * k3));
    float k5 = feval(xv + H * (A51 * k1 + A52 * k2 + A53 * k3 + A54 * k4));
    float k6 = feval(xv + H * (A61 * k1 + A62 * k2 + A63 * k3 + A64 * k4 + A65 * k5));
    xv = xv + H * (B1 * k1 + B3 * k3 + B4 * k4 + B5 * k5 + B6 * k6);
  }

  float o = (xv - thr > 0.f) ? 1.f : 0.f;
  if (RES) {
    double res = fma(g_ysc[idx], g_prm[128 + c], g_prm[192 + c]);
    outf[idx] = (float)((double)o + res);
  } else {
    g_y1[idx] = (double)o;   // in-place spike, exact {0,1}
  }
}

// ---------------- launch ----------------------------------------------------
extern "C" void kernel_launch(void* const* d_in, const int* in_sizes, int n_in,
                              void* d_out, int out_size, void* d_ws, size_t ws_size,
                              hipStream_t stream)
{
  const float* x    = (const float*)d_in[0];
  const float* c1w  = (const float*)d_in[1];
  const float* c1b  = (const float*)d_in[2];
  const float* bn1g = (const float*)d_in[3];
  const float* bn1b = (const float*)d_in[4];
  const float* o1w  = (const float*)d_in[5];
  const float* t1w  = (const float*)d_in[6];
  const float* t1b  = (const float*)d_in[7];
  const float* c2w  = (const float*)d_in[8];
  const float* bn2g = (const float*)d_in[9];
  const float* bn2b = (const float*)d_in[10];
  const float* o2w  = (const float*)d_in[11];
  const float* t2w  = (const float*)d_in[12];
  const float* t2b  = (const float*)d_in[13];
  const float* scw  = (const float*)d_in[14];
  const float* scg  = (const float*)d_in[15];
  const float* scb  = (const float*)d_in[16];

  prep_kernel<<<144, 256, 0, stream>>>(c1w, c1b, scw, c2w);

  conv1_sc_kernel<<<1024, 256, 0, stream>>>(x);
  reduce_stats<<<256, 256, 0, stream>>>(0);
  bn_params<<<1, 64, 0, stream>>>(0, 64, 0, bn1g, bn1b);
  bn_params<<<1, 64, 0, stream>>>(128, 192, 128, scg, scb);

  ode_kernel<false><<<16384, 256, 0, stream>>>(0, o1w, t1w, t1b, 0.3f, nullptr);

  conv2_kernel<<<1024, 256, 0, stream>>>();
  reduce_stats<<<128, 256, 0, stream>>>(256);
  bn_params<<<1, 64, 0, stream>>>(256, 320, 256, bn2g, bn2b);

  ode_kernel<true><<<16384, 256, 0, stream>>>(256, o2w, t2w, t2b, 0.5f, (float*)d_out);
}

// Round 5
// 3057.039 us; speedup vs baseline: 1.8089x; 1.8089x over previous
//
#include <hip/hip_runtime.h>
#include <math.h>

// ---------------------------------------------------------------------------
// R5: R4's f32 ODE spilled (FETCH 3.2GB, WRITE 1.3GB, VALUBusy 33%): full
// unroll of 6 fevals x 64 iters let the scheduler hoist ds_reads past the
// 128-VGPR cap. Fix: non-unrolled 8-step chunk loop (runtime readlane index,
// per-chunk ds_read base) bounds live ranges + code size. Convs/BN stay f64.
// ---------------------------------------------------------------------------

#define NELEM (16 * 64 * 64 * 64)  // 4194304, B*C*H*W with C=64

__device__ double g_y1[NELEM];    // conv1 out (f64) -> overwritten in-place by spike1
__device__ double g_ysc[NELEM];   // 1x1 shortcut conv out (f64)
__device__ double g_y2[NELEM];    // conv2 out (f64)
__device__ double g_part[384][1024];  // per-block stat partials
__device__ double g_stats[384];
__device__ double g_prm[384];     // [0]=bn1 sc,[64]=bn1 sh,[128]=sc sc,[192]=sc sh,
                                  // [256]=bn2 sc,[320]=bn2 sh
__device__ double g_w1d[64 * 32 * 9];
__device__ double g_b1d[64];
__device__ double g_scwd[64 * 32];
__device__ double g_w2d[64 * 64 * 9];

// ---------------- weight upconvert (f32 -> f64, exact) ----------------------
__global__ void prep_kernel(const float* __restrict__ w1, const float* __restrict__ b1,
                            const float* __restrict__ scw, const float* __restrict__ w2)
{
  int i = blockIdx.x * 256 + threadIdx.x;
  if (i < 64 * 32 * 9) g_w1d[i] = (double)w1[i];
  if (i < 64)          g_b1d[i] = (double)b1[i];
  if (i < 64 * 32)     g_scwd[i] = (double)scw[i];
  if (i < 64 * 64 * 9) g_w2d[i] = (double)w2[i];
}

__device__ __forceinline__ double wave_sum64(double v) {
#pragma unroll
  for (int m = 1; m < 64; m <<= 1) v += __shfl_xor(v, m);
  return v;
}

// ---------------- conv1 (3x3, 32->64, bias) + sc conv (1x1) -----------------
__global__ __launch_bounds__(256) void conv1_sc_kernel(const float* __restrict__ x)
{
  const int b = blockIdx.x >> 6, h = blockIdx.x & 63;
  const int w = threadIdx.x & 63;
  const int cog = __builtin_amdgcn_readfirstlane(threadIdx.x >> 6);  // 0..3
  __shared__ float xs[3][32][64];
  for (int i = threadIdx.x; i < 3 * 32 * 64; i += 256) {
    int kh = i >> 11, ci = (i >> 6) & 31, ww = i & 63;
    int hh = h + kh - 1;
    xs[kh][ci][ww] = ((unsigned)hh < 64u) ? x[((b * 32 + ci) << 12) + (hh << 6) + ww] : 0.f;
  }
  __syncthreads();

  double acc[16], asc[16];
#pragma unroll
  for (int i = 0; i < 16; ++i) { acc[i] = g_b1d[cog * 16 + i]; asc[i] = 0.0; }

  for (int ci = 0; ci < 32; ++ci) {
    double xv[3][3];
#pragma unroll
    for (int kh = 0; kh < 3; ++kh) {
      xv[kh][0] = (w > 0)  ? (double)xs[kh][ci][w - 1] : 0.0;
      xv[kh][1] = (double)xs[kh][ci][w];
      xv[kh][2] = (w < 63) ? (double)xs[kh][ci][w + 1] : 0.0;
    }
#pragma unroll
    for (int i = 0; i < 16; ++i) {
      const int co = cog * 16 + i;
      const double* wp = &g_w1d[(co * 32 + ci) * 9];
      double a = acc[i];
#pragma unroll
      for (int k = 0; k < 9; ++k) a = fma(xv[k / 3][k % 3], wp[k], a);
      acc[i] = a;
      asc[i] = fma(xv[1][1], g_scwd[co * 32 + ci], asc[i]);
    }
  }

#pragma unroll
  for (int i = 0; i < 16; ++i) {
    const int co = cog * 16 + i;
    const int oidx = ((b * 64 + co) << 12) + (h << 6) + w;
    double v = acc[i], u = asc[i];
    g_y1[oidx] = v;
    g_ysc[oidx] = u;
    double s = wave_sum64(v), q = wave_sum64(v * v);
    double ss = wave_sum64(u), qq = wave_sum64(u * u);
    if (w == 0) {
      g_part[co][blockIdx.x] = s;        g_part[64 + co][blockIdx.x] = q;
      g_part[128 + co][blockIdx.x] = ss; g_part[192 + co][blockIdx.x] = qq;
    }
  }
}

// ---------------- conv2 (3x3, 64->64, no bias) ------------------------------
__global__ __launch_bounds__(256) void conv2_kernel()
{
  const int b = blockIdx.x >> 6, h = blockIdx.x & 63;
  const int w = threadIdx.x & 63;
  const int cog = __builtin_amdgcn_readfirstlane(threadIdx.x >> 6);
  __shared__ float xs[3][64][64];   // spike values {0,1}: f32 exact
  for (int i = threadIdx.x; i < 3 * 64 * 64; i += 256) {
    int kh = i >> 12, ci = (i >> 6) & 63, ww = i & 63;
    int hh = h + kh - 1;
    xs[kh][ci][ww] = ((unsigned)hh < 64u) ? (float)g_y1[((b * 64 + ci) << 12) + (hh << 6) + ww] : 0.f;
  }
  __syncthreads();

  double acc[16];
#pragma unroll
  for (int i = 0; i < 16; ++i) acc[i] = 0.0;

  for (int ci = 0; ci < 64; ++ci) {
    double xv[3][3];
#pragma unroll
    for (int kh = 0; kh < 3; ++kh) {
      xv[kh][0] = (w > 0)  ? (double)xs[kh][ci][w - 1] : 0.0;
      xv[kh][1] = (double)xs[kh][ci][w];
      xv[kh][2] = (w < 63) ? (double)xs[kh][ci][w + 1] : 0.0;
    }
#pragma unroll
    for (int i = 0; i < 16; ++i) {
      const int co = cog * 16 + i;
      const double* wp = &g_w2d[(co * 64 + ci) * 9];
      double a = acc[i];
#pragma unroll
      for (int k = 0; k < 9; ++k) a = fma(xv[k / 3][k % 3], wp[k], a);
      acc[i] = a;
    }
  }

#pragma unroll
  for (int i = 0; i < 16; ++i) {
    const int co = cog * 16 + i;
    double v = acc[i];
    g_y2[((b * 64 + co) << 12) + (h << 6) + w] = v;
    double s = wave_sum64(v), q = wave_sum64(v * v);
    if (w == 0) { g_part[256 + co][blockIdx.x] = s; g_part[320 + co][blockIdx.x] = q; }
  }
}

// ---------------- deterministic stat reduction ------------------------------
__global__ __launch_bounds__(256) void reduce_stats(int base)
{
  const int row = base + blockIdx.x;
  const int t = threadIdx.x;
  double s = g_part[row][t] + g_part[row][t + 256] + g_part[row][t + 512] + g_part[row][t + 768];
  s = wave_sum64(s);
  __shared__ double ls[4];
  if ((t & 63) == 0) ls[t >> 6] = s;
  __syncthreads();
  if (t == 0) g_stats[row] = ls[0] + ls[1] + ls[2] + ls[3];
}

// ---------------- BN params: scale = g*rstd, shift = b - m*scale ------------
__global__ void bn_params(int s_off, int q_off, int p_off,
                          const float* __restrict__ g, const float* __restrict__ bta)
{
  int c = threadIdx.x;
  const double inv = 1.0 / 65536.0;
  double m = g_stats[s_off + c] * inv;
  double v = g_stats[q_off + c] * inv - m * m;
  double rstd = 1.0 / sqrt(v + 1e-5);
  double sc = (double)g[c] * rstd;
  g_prm[p_off + c] = sc;
  g_prm[p_off + 64 + c] = (double)bta[c] - m * sc;
}

// ---------------- ODE (dopri5, 5 steps, f32) + spike [+ residual] -----------
// f32 weights in LDS; wos row-major (lane j = column j), wts transposed.
// Inner matvec = NON-UNROLLED 8-step chunk loop: bounds scheduler hoisting
// (R4 spill fix) and keeps feval code ~8x smaller.
__device__ __forceinline__ float bcast_f(float v, int l) {
  return __uint_as_float(__builtin_amdgcn_readlane(__float_as_uint(v), l));
}

template <bool RES>
__global__ __launch_bounds__(256, 4) void ode_kernel(
    int prm_off, const float* __restrict__ wodep, const float* __restrict__ wtgp,
    const float* __restrict__ tgbp, float thr, float* __restrict__ outf)
{
  __shared__ float wos[64 * 64];
  __shared__ float wts[64 * 64];
  for (int t = threadIdx.x; t < 4096; t += 256) {
    wos[t] = wodep[t];
    int i = t >> 6, j = t & 63;
    wts[t] = wtgp[j * 64 + i];
  }
  __syncthreads();

  const int lane = threadIdx.x & 63;
  const int wv = __builtin_amdgcn_readfirstlane(threadIdx.x >> 6);
  const float tb = tgbp[lane];

  auto feval = [&](float xsv) -> float {
    float ao0 = 0.f, ao1 = 0.f, ao2 = 0.f, ao3 = 0.f;
    float at0 = 0.f, at1 = 0.f, at2 = 0.f, at3 = 0.f;
#pragma unroll 1
    for (int ib = 0; ib < 64; ib += 8) {      // runtime ib: loop NOT unrolled
      const float* wop = &wos[ib * 64 + lane];
      const float* wtp = &wts[ib * 64 + lane];
#pragma unroll
      for (int u = 0; u < 8; u += 4) {
        float x0 = bcast_f(xsv, ib + u);      // v_readlane, SGPR lane index
        float x1 = bcast_f(xsv, ib + u + 1);
        float x2 = bcast_f(xsv, ib + u + 2);
        float x3 = bcast_f(xsv, ib + u + 3);
        ao0 = fmaf(x0, wop[(u + 0) * 64], ao0);
        at0 = fmaf(x0, wtp[(u + 0) * 64], at0);
        ao1 = fmaf(x1, wop[(u + 1) * 64], ao1);
        at1 = fmaf(x1, wtp[(u + 1) * 64], at1);
        ao2 = fmaf(x2, wop[(u + 2) * 64], ao2);
        at2 = fmaf(x2, wtp[(u + 2) * 64], at2);
        ao3 = fmaf(x3, wop[(u + 3) * 64], ao3);
        at3 = fmaf(x3, wtp[(u + 3) * 64], at3);
      }
    }
    float ao = (ao0 + ao1) + (ao2 + ao3);
    float z = ((at0 + at1) + (at2 + at3)) + tb;
    float g = 0.5f * ao * (1.f + erff(ao * 0.70710678118654752440f));
    float e = expf(-z);
    float tf = 1.f - 1.f / (2.f + e);   // == (1+e)/(2+e); e=inf -> 1, e=0 -> 0.5
    return g * tf;
  };

  const float H = (float)(1.0 / 5.0);
  const float A21 = (float)(1.0 / 5.0);
  const float A31 = (float)(3.0 / 40.0), A32 = (float)(9.0 / 40.0);
  const float A41 = (float)(44.0 / 45.0), A42 = (float)(-56.0 / 15.0), A43 = (float)(32.0 / 9.0);
  const float A51 = (float)(19372.0 / 6561.0), A52 = (float)(-25360.0 / 2187.0),
              A53 = (float)(64448.0 / 6561.0), A54 = (float)(-212.0 / 729.0);
  const float A61 = (float)(9017.0 / 3168.0), A62 = (float)(-355.0 / 33.0),
              A63 = (float)(46732.0 / 5247.0), A64 = (float)(49.0 / 176.0),
              A65 = (float)(-5103.0 / 18656.0);
  const float B1 = (float)(35.0 / 384.0), B3 = (float)(500.0 / 1113.0),
              B4 = (float)(125.0 / 192.0), B5 = (float)(-2187.0 / 6784.0),
              B6 = (float)(11.0 / 84.0);

  const int row = blockIdx.x * 4 + wv;      // one row per wave
  const int c = (row >> 6) & 63;
  const int idx = (row << 6) + lane;
  const double psc = g_prm[prm_off + c], psh = g_prm[prm_off + 64 + c];
  float xv = (float)fma(RES ? g_y2[idx] : g_y1[idx], psc, psh);  // exact BN in f64

#pragma unroll 1
  for (int st5 = 0; st5 < 5; ++st5) {
    float k1 = feval(xv);
    float k2 = feval(xv + H * (A21 * k1));
    float k3 = feval(xv + H * (A31 * k1 + A32 * k2));
    float k4 = feval(xv + H * (A41 * k1 + A42 * k2 + A43 * k3));
    float k5 = feval(xv + H * (A51 * k1 + A52 * k2 + A53 * k3 + A54 * k4));
    float k6 = feval(xv + H * (A61 * k1 + A62 * k2 + A63 * k3 + A64 * k4 + A65 * k5));
    xv = xv + H * (B1 * k1 + B3 * k3 + B4 * k4 + B5 * k5 + B6 * k6);
  }

  float o = (xv - thr > 0.f) ? 1.f : 0.f;
  if (RES) {
    double res = fma(g_ysc[idx], g_prm[128 + c], g_prm[192 + c]);
    outf[idx] = (float)((double)o + res);
  } else {
    g_y1[idx] = (double)o;   // in-place spike, exact {0,1}
  }
}

// ---------------- launch ----------------------------------------------------
extern "C" void kernel_launch(void* const* d_in, const int* in_sizes, int n_in,
                              void* d_out, int out_size, void* d_ws, size_t ws_size,
                              hipStream_t stream)
{
  const float* x    = (const float*)d_in[0];
  const float* c1w  = (const float*)d_in[1];
  const float* c1b  = (const float*)d_in[2];
  const float* bn1g = (const float*)d_in[3];
  const float* bn1b = (const float*)d_in[4];
  const float* o1w  = (const float*)d_in[5];
  const float* t1w  = (const float*)d_in[6];
  const float* t1b  = (const float*)d_in[7];
  const float* c2w  = (const float*)d_in[8];
  const float* bn2g = (const float*)d_in[9];
  const float* bn2b = (const float*)d_in[10];
  const float* o2w  = (const float*)d_in[11];
  const float* t2w  = (const float*)d_in[12];
  const float* t2b  = (const float*)d_in[13];
  const float* scw  = (const float*)d_in[14];
  const float* scg  = (const float*)d_in[15];
  const float* scb  = (const float*)d_in[16];

  prep_kernel<<<144, 256, 0, stream>>>(c1w, c1b, scw, c2w);

  conv1_sc_kernel<<<1024, 256, 0, stream>>>(x);
  reduce_stats<<<256, 256, 0, stream>>>(0);
  bn_params<<<1, 64, 0, stream>>>(0, 64, 0, bn1g, bn1b);
  bn_params<<<1, 64, 0, stream>>>(128, 192, 128, scg, scb);

  ode_kernel<false><<<16384, 256, 0, stream>>>(0, o1w, t1w, t1b, 0.3f, nullptr);

  conv2_kernel<<<1024, 256, 0, stream>>>();
  reduce_stats<<<128, 256, 0, stream>>>(256);
  bn_params<<<1, 64, 0, stream>>>(256, 320, 256, bn2g, bn2b);

  ode_kernel<true><<<16384, 256, 0, stream>>>(256, o2w, t2w, t2b, 0.5f, (float*)d_out);
}

// Round 7
// 1764.454 us; speedup vs baseline: 3.1341x; 1.7326x over previous
//
#include <hip/hip_runtime.h>
#include <math.h>

// ---------------------------------------------------------------------------
// R7 = R6 with the crash fixed: R6 passed __device__ globals (g_y1f etc.) as
// kernel args FROM HOST CODE -> host shadow address -> device memory fault ->
// abort. Globals are now referenced only inside device code (template-picked).
// ODE design (unchanged from R6 theory): R5 was LDS-BW-bound (8192 dwords/
// feval). Weights live in VGPRs (static unroll); x is broadcast via LDS
// (1 ds_write_b32 + 16 same-addr ds_read_b128 = ~128 dwords/feval).
// Convs f32 (weights direct), BN stats/params still deterministic f64.
// ---------------------------------------------------------------------------

#define NELEM (16 * 64 * 64 * 64)  // 4194304, B*C*H*W with C=64

__device__ float  g_y1f[NELEM];   // conv1 out -> overwritten in-place by spike1
__device__ float  g_yscf[NELEM];  // 1x1 shortcut conv out
__device__ float  g_y2f[NELEM];   // conv2 out
__device__ double g_part[384][1024];  // per-block stat partials (f64)
__device__ double g_stats[384];
__device__ double g_prm[384];     // [0]=bn1 sc,[64]=bn1 sh,[128]=sc sc,[192]=sc sh,
                                  // [256]=bn2 sc,[320]=bn2 sh

__device__ __forceinline__ double wave_sum64(double v) {
#pragma unroll
  for (int m = 1; m < 64; m <<= 1) v += __shfl_xor(v, m);
  return v;
}

// ---------------- conv1 (3x3, 32->64, bias, f32) + sc conv (1x1) ------------
__global__ __launch_bounds__(256) void conv1_sc_kernel(
    const float* __restrict__ x, const float* __restrict__ w1,
    const float* __restrict__ b1, const float* __restrict__ scw)
{
  const int b = blockIdx.x >> 6, h = blockIdx.x & 63;
  const int w = threadIdx.x & 63;
  const int cog = __builtin_amdgcn_readfirstlane(threadIdx.x >> 6);  // 0..3
  __shared__ float xs[3][32][64];
  for (int i = threadIdx.x; i < 3 * 32 * 64; i += 256) {
    int kh = i >> 11, ci = (i >> 6) & 31, ww = i & 63;
    int hh = h + kh - 1;
    xs[kh][ci][ww] = ((unsigned)hh < 64u) ? x[((b * 32 + ci) << 12) + (hh << 6) + ww] : 0.f;
  }
  __syncthreads();

  float acc[16], asc[16];
#pragma unroll
  for (int i = 0; i < 16; ++i) { acc[i] = b1[cog * 16 + i]; asc[i] = 0.f; }

  for (int ci = 0; ci < 32; ++ci) {
    float xv[3][3];
#pragma unroll
    for (int kh = 0; kh < 3; ++kh) {
      xv[kh][0] = (w > 0)  ? xs[kh][ci][w - 1] : 0.f;
      xv[kh][1] = xs[kh][ci][w];
      xv[kh][2] = (w < 63) ? xs[kh][ci][w + 1] : 0.f;
    }
#pragma unroll
    for (int i = 0; i < 16; ++i) {
      const int co = cog * 16 + i;
      const float* wp = &w1[(co * 32 + ci) * 9];  // wave-uniform -> s_load
      float a = acc[i];
#pragma unroll
      for (int k = 0; k < 9; ++k) a = fmaf(xv[k / 3][k % 3], wp[k], a);
      acc[i] = a;
      asc[i] = fmaf(xv[1][1], scw[co * 32 + ci], asc[i]);
    }
  }

#pragma unroll
  for (int i = 0; i < 16; ++i) {
    const int co = cog * 16 + i;
    const int oidx = ((b * 64 + co) << 12) + (h << 6) + w;
    float v = acc[i], u = asc[i];
    g_y1f[oidx] = v;
    g_yscf[oidx] = u;
    double dv = (double)v, du = (double)u;
    double s = wave_sum64(dv), q = wave_sum64(dv * dv);
    double ss = wave_sum64(du), qq = wave_sum64(du * du);
    if (w == 0) {
      g_part[co][blockIdx.x] = s;        g_part[64 + co][blockIdx.x] = q;
      g_part[128 + co][blockIdx.x] = ss; g_part[192 + co][blockIdx.x] = qq;
    }
  }
}

// ---------------- conv2 (3x3, 64->64, no bias, f32) -------------------------
__global__ __launch_bounds__(256) void conv2_kernel(const float* __restrict__ w2)
{
  const int b = blockIdx.x >> 6, h = blockIdx.x & 63;
  const int w = threadIdx.x & 63;
  const int cog = __builtin_amdgcn_readfirstlane(threadIdx.x >> 6);
  __shared__ float xs[3][64][64];   // spike values {0,1}
  for (int i = threadIdx.x; i < 3 * 64 * 64; i += 256) {
    int kh = i >> 12, ci = (i >> 6) & 63, ww = i & 63;
    int hh = h + kh - 1;
    xs[kh][ci][ww] = ((unsigned)hh < 64u) ? g_y1f[((b * 64 + ci) << 12) + (hh << 6) + ww] : 0.f;
  }
  __syncthreads();

  float acc[16];
#pragma unroll
  for (int i = 0; i < 16; ++i) acc[i] = 0.f;

  for (int ci = 0; ci < 64; ++ci) {
    float xv[3][3];
#pragma unroll
    for (int kh = 0; kh < 3; ++kh) {
      xv[kh][0] = (w > 0)  ? xs[kh][ci][w - 1] : 0.f;
      xv[kh][1] = xs[kh][ci][w];
      xv[kh][2] = (w < 63) ? xs[kh][ci][w + 1] : 0.f;
    }
#pragma unroll
    for (int i = 0; i < 16; ++i) {
      const int co = cog * 16 + i;
      const float* wp = &w2[(co * 64 + ci) * 9];
      float a = acc[i];
#pragma unroll
      for (int k = 0; k < 9; ++k) a = fmaf(xv[k / 3][k % 3], wp[k], a);
      acc[i] = a;
    }
  }

#pragma unroll
  for (int i = 0; i < 16; ++i) {
    const int co = cog * 16 + i;
    float v = acc[i];
    g_y2f[((b * 64 + co) << 12) + (h << 6) + w] = v;
    double dv = (double)v;
    double s = wave_sum64(dv), q = wave_sum64(dv * dv);
    if (w == 0) { g_part[256 + co][blockIdx.x] = s; g_part[320 + co][blockIdx.x] = q; }
  }
}

// ---------------- deterministic stat reduction ------------------------------
__global__ __launch_bounds__(256) void reduce_stats(int base)
{
  const int row = base + blockIdx.x;
  const int t = threadIdx.x;
  double s = g_part[row][t] + g_part[row][t + 256] + g_part[row][t + 512] + g_part[row][t + 768];
  s = wave_sum64(s);
  __shared__ double ls[4];
  if ((t & 63) == 0) ls[t >> 6] = s;
  __syncthreads();
  if (t == 0) g_stats[row] = ls[0] + ls[1] + ls[2] + ls[3];
}

// ---------------- BN params: scale = g*rstd, shift = b - m*scale ------------
__global__ void bn_params(int s_off, int q_off, int p_off,
                          const float* __restrict__ g, const float* __restrict__ bta)
{
  int c = threadIdx.x;
  const double inv = 1.0 / 65536.0;
  double m = g_stats[s_off + c] * inv;
  double v = g_stats[q_off + c] * inv - m * m;
  double rstd = 1.0 / sqrt(v + 1e-5);
  double sc = (double)g[c] * rstd;
  g_prm[p_off + c] = sc;
  g_prm[p_off + 64 + c] = (double)bta[c] - m * sc;
}

// ---------------- ODE (dopri5, 5 steps, f32) + spike [+ residual] -----------
// Weights in VGPRs (wo[i]=w_ode[i][lane], wt[i]=tg_w[lane][i]; static unroll).
// x broadcast via LDS: 1 ds_write_b32 + 16 same-addr ds_read_b128 per feval.
// Input/output buffers selected INSIDE device code (R6 crash fix).
template <bool RES>
__global__ __launch_bounds__(256, 2) void ode_kernel(
    int prm_off, const float* __restrict__ wodep, const float* __restrict__ wtgp,
    const float* __restrict__ tgbp, float thr, float* __restrict__ outf)
{
  __shared__ float wosl[4096];
  __shared__ float wtsl[4096];
  __shared__ __align__(16) float xbuf[4][64];
  for (int t = threadIdx.x; t < 4096; t += 256) {
    wosl[t] = wodep[t];                           // w_ode row-major
    wtsl[t] = wtgp[(t & 63) * 64 + (t >> 6)];     // wtsl[i*64+j] = tg_w[j][i]
  }
  __syncthreads();

  const int lane = threadIdx.x & 63;
  const int wv = __builtin_amdgcn_readfirstlane(threadIdx.x >> 6);
  float wo[64], wt[64];                            // static-indexed -> registers
#pragma unroll
  for (int i = 0; i < 64; ++i) wo[i] = wosl[(i << 6) + lane];
#pragma unroll
  for (int i = 0; i < 64; ++i) wt[i] = wtsl[(i << 6) + lane];
  const float tb = tgbp[lane];
  float* __restrict__ xrow = xbuf[wv];

  auto feval = [&](float xs) -> float {
    __builtin_amdgcn_sched_barrier(0);   // fence cross-feval motion
    xrow[lane] = xs;                     // ds_write_b32; waitcnt auto-inserted
    float ao0 = 0.f, ao1 = 0.f, ao2 = 0.f, ao3 = 0.f;
    float at0 = 0.f, at1 = 0.f, at2 = 0.f, at3 = 0.f;
#pragma unroll
    for (int i = 0; i < 64; i += 4) {
      float4 xq = *reinterpret_cast<const float4*>(&xrow[i]);  // broadcast b128
      ao0 = fmaf(xq.x, wo[i + 0], ao0);  at0 = fmaf(xq.x, wt[i + 0], at0);
      ao1 = fmaf(xq.y, wo[i + 1], ao1);  at1 = fmaf(xq.y, wt[i + 1], at1);
      ao2 = fmaf(xq.z, wo[i + 2], ao2);  at2 = fmaf(xq.z, wt[i + 2], at2);
      ao3 = fmaf(xq.w, wo[i + 3], ao3);  at3 = fmaf(xq.w, wt[i + 3], at3);
    }
    float ao = (ao0 + ao1) + (ao2 + ao3);
    float z = ((at0 + at1) + (at2 + at3)) + tb;
    float g = 0.5f * ao * (1.f + erff(ao * 0.70710678118654752440f));
    float e = expf(-z);
    float tf = 1.f - 1.f / (2.f + e);   // == (1+e)/(2+e); e=inf -> 1
    return g * tf;
  };

  const float H = (float)(1.0 / 5.0);
  const float A21 = (float)(1.0 / 5.0);
  const float A31 = (float)(3.0 / 40.0), A32 = (float)(9.0 / 40.0);
  const float A41 = (float)(44.0 / 45.0), A42 = (float)(-56.0 / 15.0), A43 = (float)(32.0 / 9.0);
  const float A51 = (float)(19372.0 / 6561.0), A52 = (float)(-25360.0 / 2187.0),
              A53 = (float)(64448.0 / 6561.0), A54 = (float)(-212.0 / 729.0);
  const float A61 = (float)(9017.0 / 3168.0), A62 = (float)(-355.0 / 33.0),
              A63 = (float)(46732.0 / 5247.0), A64 = (float)(49.0 / 176.0),
              A65 = (float)(-5103.0 / 18656.0);
  const float B1 = (float)(35.0 / 384.0), B3 = (float)(500.0 / 1113.0),
              B4 = (float)(125.0 / 192.0), B5 = (float)(-2187.0 / 6784.0),
              B6 = (float)(11.0 / 84.0);

  const int base = blockIdx.x * 8 + wv * 2;   // 2 rows per wave
#pragma unroll 1
  for (int r = 0; r < 2; ++r) {
    const int row = base + r;
    const int c = (row >> 6) & 63;
    const int idx = (row << 6) + lane;
    const double psc = g_prm[prm_off + c], psh = g_prm[prm_off + 64 + c];
    const float yv = RES ? g_y2f[idx] : g_y1f[idx];
    float xv = (float)fma((double)yv, psc, psh);  // exact BN transform

#pragma unroll 1
    for (int st5 = 0; st5 < 5; ++st5) {
      float k1 = feval(xv);
      float k2 = feval(xv + H * (A21 * k1));
      float k3 = feval(xv + H * (A31 * k1 + A32 * k2));
      float k4 = feval(xv + H * (A41 * k1 + A42 * k2 + A43 * k3));
      float k5 = feval(xv + H * (A51 * k1 + A52 * k2 + A53 * k3 + A54 * k4));
      float k6 = feval(xv + H * (A61 * k1 + A62 * k2 + A63 * k3 + A64 * k4 + A65 * k5));
      xv = xv + H * (B1 * k1 + B3 * k3 + B4 * k4 + B5 * k5 + B6 * k6);
    }

    float o = (xv - thr > 0.f) ? 1.f : 0.f;
    if (RES) {
      double res = fma((double)g_yscf[idx], g_prm[128 + c], g_prm[192 + c]);
      outf[idx] = (float)((double)o + res);
    } else {
      g_y1f[idx] = o;   // in-place spike, exact {0,1}
    }
  }
}

// ---------------- launch ----------------------------------------------------
extern "C" void kernel_launch(void* const* d_in, const int* in_sizes, int n_in,
                              void* d_out, int out_size, void* d_ws, size_t ws_size,
                              hipStream_t stream)
{
  const float* x    = (const float*)d_in[0];
  const float* c1w  = (const float*)d_in[1];
  const float* c1b  = (const float*)d_in[2];
  const float* bn1g = (const float*)d_in[3];
  const float* bn1b = (const float*)d_in[4];
  const float* o1w  = (const float*)d_in[5];
  const float* t1w  = (const float*)d_in[6];
  const float* t1b  = (const float*)d_in[7];
  const float* c2w  = (const float*)d_in[8];
  const float* bn2g = (const float*)d_in[9];
  const float* bn2b = (const float*)d_in[10];
  const float* o2w  = (const float*)d_in[11];
  const float* t2w  = (const float*)d_in[12];
  const float* t2b  = (const float*)d_in[13];
  const float* scw  = (const float*)d_in[14];
  const float* scg  = (const float*)d_in[15];
  const float* scb  = (const float*)d_in[16];

  conv1_sc_kernel<<<1024, 256, 0, stream>>>(x, c1w, c1b, scw);
  reduce_stats<<<256, 256, 0, stream>>>(0);
  bn_params<<<1, 64, 0, stream>>>(0, 64, 0, bn1g, bn1b);
  bn_params<<<1, 64, 0, stream>>>(128, 192, 128, scg, scb);

  ode_kernel<false><<<8192, 256, 0, stream>>>(0, o1w, t1w, t1b, 0.3f, nullptr);

  conv2_kernel<<<1024, 256, 0, stream>>>(c2w);
  reduce_stats<<<128, 256, 0, stream>>>(256);
  bn_params<<<1, 64, 0, stream>>>(256, 320, 256, bn2g, bn2b);

  ode_kernel<true><<<8192, 256, 0, stream>>>(256, o2w, t2w, t2b, 0.5f, (float*)d_out);
}